// Round 1
// baseline (460.714 us; speedup 1.0000x reference)
//
#include <hip/hip_runtime.h>
#include <hip/hip_fp16.h>
#include <math.h>

#define NLV 8
#define NF 4
#define HSZ 8192
#define TRES 25
#define PRIME 2654435761u

struct Scales { float s[NLV]; };

// Blend two time slices into one fp16 table in workspace.
// NEW layout per level l: 8192 slots x 8 B, slot h = {half2(f0,f1), half2(f2,f3)}
// -> one ds_read_b64 per bilinear corner in the encode kernel.
__global__ __launch_bounds__(256) void blend_kernel(
    const float* __restrict__ table, const float* __restrict__ tptr,
    __half2* __restrict__ bt)
{
    int i = blockIdx.x * 256 + threadIdx.x;       // 0..65535 = l*8192 + h
    float t = *tptr;
    float idx = t * (float)(TRES - 1);            // fp32, matches ref
    float fi1 = floorf(idx);
    float fi2 = ceilf(idx);
    float w2 = idx - fi1;
    float w1 = 1.0f - w2;
    size_t off1 = (size_t)(int)fi1 * (size_t)(NLV * HSZ * NF);
    size_t off2 = (size_t)(int)fi2 * (size_t)(NLV * HSZ * NF);
    float4 a = ((const float4*)(table + off1))[i];
    float4 b = ((const float4*)(table + off2))[i];
    float4 r;
    r.x = w1 * a.x + w2 * b.x;
    r.y = w1 * a.y + w2 * b.y;
    r.z = w1 * a.z + w2 * b.z;
    r.w = w1 * a.w + w2 * b.w;
    bt[2 * (size_t)i]     = __floats2half2_rn(r.x, r.y);
    bt[2 * (size_t)i + 1] = __floats2half2_rn(r.z, r.w);
}

__device__ __forceinline__ float2 h2f(unsigned u) {
    return __half22float2(__builtin_bit_cast(__half2, u));
}

// One level, one point: 4 hashed corners, each an 8-B LDS read, bilinear blend.
__device__ __forceinline__ float4 gather_lvl(const uint2* tbl, float2 p, float scale)
{
    // separate mul+add rounding (no fma) to match numpy floor/frac exactly
    float px = __fadd_rn(__fmul_rn(p.x, scale), 0.5f);
    float py = __fadd_rn(__fmul_rn(p.y, scale), 0.5f);
    float fx0 = floorf(px), fy0 = floorf(py);
    float fx = px - fx0, fy = py - fy0;
    unsigned ix = (unsigned)(int)fx0;
    unsigned iy = (unsigned)(int)fy0;
    unsigned hy0 = iy * PRIME;
    unsigned hy1 = hy0 + PRIME;                   // (iy+1)*PRIME mod 2^32
    unsigned h00 = (ix         ^ hy0) & (HSZ - 1);
    unsigned h01 = (ix         ^ hy1) & (HSZ - 1);
    unsigned h10 = ((ix + 1u)  ^ hy0) & (HSZ - 1);
    unsigned h11 = ((ix + 1u)  ^ hy1) & (HSZ - 1);
    uint2 v00 = tbl[h00];
    uint2 v01 = tbl[h01];
    uint2 v10 = tbl[h10];
    uint2 v11 = tbl[h11];
    float gx = 1.0f - fx, gy = 1.0f - fy;
    float w00 = gx * gy, w01 = gx * fy, w10 = fx * gy, w11 = fx * fy;
    float2 a00 = h2f(v00.x), b00 = h2f(v00.y);
    float2 a01 = h2f(v01.x), b01 = h2f(v01.y);
    float2 a10 = h2f(v10.x), b10 = h2f(v10.y);
    float2 a11 = h2f(v11.x), b11 = h2f(v11.y);
    float4 r;
    r.x = w00 * a00.x + w01 * a01.x + w10 * a10.x + w11 * a11.x;
    r.y = w00 * a00.y + w01 * a01.y + w10 * a10.y + w11 * a11.y;
    r.z = w00 * b00.x + w01 * b01.x + w10 * b10.x + w11 * b11.x;
    r.w = w00 * b00.y + w01 * b01.y + w10 * b10.y + w11 * b11.y;
    return r;
}

// 4 points/thread (4096 pts/block, 489 blocks), double-buffered 128 KB LDS.
// Per phase: issue next level's global loads into regs -> gather current level
// from LDS -> ds_write next level into idle buffer -> ONE barrier. Global
// latency hides under gathers; staging L2 traffic drops 4x vs 1 pt/thread.
// Output written in two 64-B-per-point groups (levels 0-3, 4-7): each group
// store is exactly one aligned 64-B line per point, acc needs only 64 VGPRs.
__global__ __launch_bounds__(1024, 4) void encode_kernel(
    const float* __restrict__ x, const float4* __restrict__ bt,
    float* __restrict__ out, int npts, Scales sc)
{
    __shared__ float4 smem[2][4096];              // 2 x 64 KB double buffer
    int tid = threadIdx.x;
    int base = blockIdx.x * 4096 + tid;
    int n0 = base, n1 = base + 1024, n2 = base + 2048, n3 = base + 3072;
    int c0 = n0 < npts ? n0 : npts - 1;
    int c1 = n1 < npts ? n1 : npts - 1;
    int c2 = n2 < npts ? n2 : npts - 1;
    int c3 = n3 < npts ? n3 : npts - 1;
    float2 p0 = ((const float2*)x)[c0];
    float2 p1 = ((const float2*)x)[c1];
    float2 p2 = ((const float2*)x)[c2];
    float2 p3 = ((const float2*)x)[c3];

    float4 acc[4][4];                             // [point][level-in-group]

    // prologue: stage level 0 into buffer 0
    {
        const float4* src = bt;
        float4 s0 = src[tid], s1 = src[tid + 1024],
               s2 = src[tid + 2048], s3 = src[tid + 3072];
        smem[0][tid] = s0; smem[0][tid + 1024] = s1;
        smem[0][tid + 2048] = s2; smem[0][tid + 3072] = s3;
    }
    __syncthreads();

    #pragma unroll
    for (int l = 0; l < NLV; ++l) {
        // issue next level's loads first: in flight during the gathers below
        float4 s0, s1, s2, s3;
        if (l < NLV - 1) {
            const float4* src = bt + (size_t)(l + 1) * 4096;
            s0 = src[tid];        s1 = src[tid + 1024];
            s2 = src[tid + 2048]; s3 = src[tid + 3072];
        }

        const uint2* tbl = (const uint2*)smem[l & 1];
        float scale = sc.s[l];
        acc[0][l & 3] = gather_lvl(tbl, p0, scale);
        acc[1][l & 3] = gather_lvl(tbl, p1, scale);
        acc[2][l & 3] = gather_lvl(tbl, p2, scale);
        acc[3][l & 3] = gather_lvl(tbl, p3, scale);

        // write next level into the idle buffer (no one reads it this phase)
        if (l < NLV - 1) {
            float4* dst = smem[(l & 1) ^ 1];
            dst[tid] = s0; dst[tid + 1024] = s1;
            dst[tid + 2048] = s2; dst[tid + 3072] = s3;
        }

        // after levels 3 and 7: flush one 64-B line per point
        if ((l & 3) == 3) {
            int g = l >> 2;
            if (n0 < npts) {
                float4* o = (float4*)(out + (size_t)n0 * 32) + g * 4;
                o[0] = acc[0][0]; o[1] = acc[0][1]; o[2] = acc[0][2]; o[3] = acc[0][3];
            }
            if (n1 < npts) {
                float4* o = (float4*)(out + (size_t)n1 * 32) + g * 4;
                o[0] = acc[1][0]; o[1] = acc[1][1]; o[2] = acc[1][2]; o[3] = acc[1][3];
            }
            if (n2 < npts) {
                float4* o = (float4*)(out + (size_t)n2 * 32) + g * 4;
                o[0] = acc[2][0]; o[1] = acc[2][1]; o[2] = acc[2][2]; o[3] = acc[2][3];
            }
            if (n3 < npts) {
                float4* o = (float4*)(out + (size_t)n3 * 32) + g * 4;
                o[0] = acc[3][0]; o[1] = acc[3][1]; o[2] = acc[3][2]; o[3] = acc[3][3];
            }
        }
        __syncthreads();   // next buffer staged; current buffer free to overwrite
    }
}

extern "C" void kernel_launch(void* const* d_in, const int* in_sizes, int n_in,
                              void* d_out, int out_size, void* d_ws, size_t ws_size,
                              hipStream_t stream) {
    const float* x     = (const float*)d_in[0];
    const float* t     = (const float*)d_in[1];
    const float* table = (const float*)d_in[2];
    float* out = (float*)d_out;
    __half2* bt = (__half2*)d_ws;       // 512 KB blended fp16 table

    int npts = in_sizes[0] / 2;

    Scales sc;
    const double l2p = log2(32768.0 / 512.0) / 7.0;   // exactly as numpy
    for (int l = 0; l < NLV; ++l)
        sc.s[l] = (float)(exp2((double)l * l2p) * 512.0 - 1.0);

    blend_kernel<<<(NLV * HSZ) / 256, 256, 0, stream>>>(table, t, bt);

    int nblocks = (npts + 4095) / 4096;
    encode_kernel<<<nblocks, 1024, 0, stream>>>(
        x, (const float4*)bt, out, npts, sc);
}

// Round 2
// 459.596 us; speedup vs baseline: 1.0024x; 1.0024x over previous
//
#include <hip/hip_runtime.h>
#include <hip/hip_fp16.h>
#include <math.h>

#define NLV 8
#define NF 4
#define HSZ 8192
#define TRES 25
#define PRIME 2654435761u

struct Scales { float s[NLV]; };

// Blend two time slices into one fp16 table in workspace.
// Layout per level l: 8192 slots x 8 B, slot h = {half2(f0,f1), half2(f2,f3)}
// -> one ds_read_b64 per bilinear corner in the encode kernel.
__global__ __launch_bounds__(256) void blend_kernel(
    const float* __restrict__ table, const float* __restrict__ tptr,
    __half2* __restrict__ bt)
{
    int i = blockIdx.x * 256 + threadIdx.x;       // 0..65535 = l*8192 + h
    float t = *tptr;
    float idx = t * (float)(TRES - 1);            // fp32, matches ref
    float fi1 = floorf(idx);
    float fi2 = ceilf(idx);
    float w2 = idx - fi1;
    float w1 = 1.0f - w2;
    size_t off1 = (size_t)(int)fi1 * (size_t)(NLV * HSZ * NF);
    size_t off2 = (size_t)(int)fi2 * (size_t)(NLV * HSZ * NF);
    float4 a = ((const float4*)(table + off1))[i];
    float4 b = ((const float4*)(table + off2))[i];
    float4 r;
    r.x = w1 * a.x + w2 * b.x;
    r.y = w1 * a.y + w2 * b.y;
    r.z = w1 * a.z + w2 * b.z;
    r.w = w1 * a.w + w2 * b.w;
    bt[2 * (size_t)i]     = __floats2half2_rn(r.x, r.y);
    bt[2 * (size_t)i + 1] = __floats2half2_rn(r.z, r.w);
}

__device__ __forceinline__ float2 h2f(unsigned u) {
    return __half22float2(__builtin_bit_cast(__half2, u));
}

// One level, one point: 4 hashed corners, each an 8-B LDS read, bilinear blend.
__device__ __forceinline__ float4 gather_lvl(const uint2* tbl, float2 p, float scale)
{
    // separate mul+add rounding (no fma) to match numpy floor/frac exactly
    float px = __fadd_rn(__fmul_rn(p.x, scale), 0.5f);
    float py = __fadd_rn(__fmul_rn(p.y, scale), 0.5f);
    float fx0 = floorf(px), fy0 = floorf(py);
    float fx = px - fx0, fy = py - fy0;
    unsigned ix = (unsigned)(int)fx0;
    unsigned iy = (unsigned)(int)fy0;
    unsigned hy0 = iy * PRIME;
    unsigned hy1 = hy0 + PRIME;                   // (iy+1)*PRIME mod 2^32
    unsigned h00 = (ix         ^ hy0) & (HSZ - 1);
    unsigned h01 = (ix         ^ hy1) & (HSZ - 1);
    unsigned h10 = ((ix + 1u)  ^ hy0) & (HSZ - 1);
    unsigned h11 = ((ix + 1u)  ^ hy1) & (HSZ - 1);
    uint2 v00 = tbl[h00];
    uint2 v01 = tbl[h01];
    uint2 v10 = tbl[h10];
    uint2 v11 = tbl[h11];
    float gx = 1.0f - fx, gy = 1.0f - fy;
    float w00 = gx * gy, w01 = gx * fy, w10 = fx * gy, w11 = fx * fy;
    float2 a00 = h2f(v00.x), b00 = h2f(v00.y);
    float2 a01 = h2f(v01.x), b01 = h2f(v01.y);
    float2 a10 = h2f(v10.x), b10 = h2f(v10.y);
    float2 a11 = h2f(v11.x), b11 = h2f(v11.y);
    float4 r;
    r.x = w00 * a00.x + w01 * a01.x + w10 * a10.x + w11 * a11.x;
    r.y = w00 * a00.y + w01 * a01.y + w10 * a10.y + w11 * a11.y;
    r.z = w00 * b00.x + w01 * b01.x + w10 * b10.x + w11 * b11.x;
    r.w = w00 * b00.y + w01 * b01.y + w10 * b10.y + w11 * b11.y;
    return r;
}

// 2 points/thread (2048 pts/block, 977 blocks), double-buffered 128 KB LDS.
// Per phase: issue next level's global loads into regs -> gather current level
// from LDS -> ds_write next level into idle buffer -> ONE barrier.
// All 8 levels accumulate in registers; each point's full 128-B output line is
// stored as 8 back-to-back float4 at the END (round-0-proven pattern: L2
// merges the 8 stores into full lines -> no allocate-fetch, WRITE = ideal).
__global__ __launch_bounds__(1024, 4) void encode_kernel(
    const float* __restrict__ x, const float4* __restrict__ bt,
    float* __restrict__ out, int npts, Scales sc)
{
    __shared__ float4 smem[2][4096];              // 2 x 64 KB double buffer
    int tid = threadIdx.x;
    int base = blockIdx.x * 2048 + tid;
    int n0 = base, n1 = base + 1024;
    int c0 = n0 < npts ? n0 : npts - 1;
    int c1 = n1 < npts ? n1 : npts - 1;
    float2 p0 = ((const float2*)x)[c0];
    float2 p1 = ((const float2*)x)[c1];

    float4 acc0[NLV], acc1[NLV];                  // 64 VGPRs of accumulator

    // prologue: stage level 0 into buffer 0
    {
        const float4* src = bt;
        smem[0][tid]        = src[tid];
        smem[0][tid + 1024] = src[tid + 1024];
        smem[0][tid + 2048] = src[tid + 2048];
        smem[0][tid + 3072] = src[tid + 3072];
    }
    __syncthreads();

    #pragma unroll
    for (int l = 0; l < NLV; ++l) {
        // issue next level's loads first: in flight during the gathers below
        float4 s0, s1, s2, s3;
        if (l < NLV - 1) {
            const float4* src = bt + (size_t)(l + 1) * 4096;
            s0 = src[tid];        s1 = src[tid + 1024];
            s2 = src[tid + 2048]; s3 = src[tid + 3072];
        }

        const uint2* tbl = (const uint2*)smem[l & 1];
        float scale = sc.s[l];
        acc0[l] = gather_lvl(tbl, p0, scale);
        acc1[l] = gather_lvl(tbl, p1, scale);

        // write next level into the idle buffer, then one barrier: it both
        // publishes the staged data and protects the buffer read this phase
        // (which phase l+1 overwrites) against early writers.
        if (l < NLV - 1) {
            float4* dst = smem[(l & 1) ^ 1];
            dst[tid] = s0; dst[tid + 1024] = s1;
            dst[tid + 2048] = s2; dst[tid + 3072] = s3;
            __syncthreads();
        }
    }

    // full 128-B line per point, 8 contiguous float4 stores back-to-back
    if (n0 < npts) {
        float4* o = (float4*)(out + (size_t)n0 * 32);
        #pragma unroll
        for (int l = 0; l < NLV; ++l) o[l] = acc0[l];
    }
    if (n1 < npts) {
        float4* o = (float4*)(out + (size_t)n1 * 32);
        #pragma unroll
        for (int l = 0; l < NLV; ++l) o[l] = acc1[l];
    }
}

extern "C" void kernel_launch(void* const* d_in, const int* in_sizes, int n_in,
                              void* d_out, int out_size, void* d_ws, size_t ws_size,
                              hipStream_t stream) {
    const float* x     = (const float*)d_in[0];
    const float* t     = (const float*)d_in[1];
    const float* table = (const float*)d_in[2];
    float* out = (float*)d_out;
    __half2* bt = (__half2*)d_ws;       // 512 KB blended fp16 table

    int npts = in_sizes[0] / 2;

    Scales sc;
    const double l2p = log2(32768.0 / 512.0) / 7.0;   // exactly as numpy
    for (int l = 0; l < NLV; ++l)
        sc.s[l] = (float)(exp2((double)l * l2p) * 512.0 - 1.0);

    blend_kernel<<<(NLV * HSZ) / 256, 256, 0, stream>>>(table, t, bt);

    int nblocks = (npts + 2047) / 2048;
    encode_kernel<<<nblocks, 1024, 0, stream>>>(
        x, (const float4*)bt, out, npts, sc);
}

// Round 3
// 418.184 us; speedup vs baseline: 1.1017x; 1.0990x over previous
//
#include <hip/hip_runtime.h>
#include <hip/hip_fp16.h>
#include <math.h>

#define NLV 8
#define NF 4
#define HSZ 8192
#define TRES 25
#define PRIME 2654435761u

struct Scales { float s[NLV]; };

// Blend two time slices into one fp16 table in workspace.
// Layout per level l: 8192 slots x 8 B, slot h = {half2(f0,f1), half2(f2,f3)}
// -> one ds_read_b64 per bilinear corner in the encode kernel.
__global__ __launch_bounds__(256) void blend_kernel(
    const float* __restrict__ table, const float* __restrict__ tptr,
    __half2* __restrict__ bt)
{
    int i = blockIdx.x * 256 + threadIdx.x;       // 0..65535 = l*8192 + h
    float t = *tptr;
    float idx = t * (float)(TRES - 1);            // fp32, matches ref
    float fi1 = floorf(idx);
    float fi2 = ceilf(idx);
    float w2 = idx - fi1;
    float w1 = 1.0f - w2;
    size_t off1 = (size_t)(int)fi1 * (size_t)(NLV * HSZ * NF);
    size_t off2 = (size_t)(int)fi2 * (size_t)(NLV * HSZ * NF);
    float4 a = ((const float4*)(table + off1))[i];
    float4 b = ((const float4*)(table + off2))[i];
    float4 r;
    r.x = w1 * a.x + w2 * b.x;
    r.y = w1 * a.y + w2 * b.y;
    r.z = w1 * a.z + w2 * b.z;
    r.w = w1 * a.w + w2 * b.w;
    bt[2 * (size_t)i]     = __floats2half2_rn(r.x, r.y);
    bt[2 * (size_t)i + 1] = __floats2half2_rn(r.z, r.w);
}

__device__ __forceinline__ float2 h2f(unsigned u) {
    return __half22float2(__builtin_bit_cast(__half2, u));
}

// One level, one point: 4 hashed corners, each an 8-B LDS read, bilinear blend.
__device__ __forceinline__ float4 gather_lvl(const uint2* tbl, float2 p, float scale)
{
    // separate mul+add rounding (no fma) to match numpy floor/frac exactly
    float px = __fadd_rn(__fmul_rn(p.x, scale), 0.5f);
    float py = __fadd_rn(__fmul_rn(p.y, scale), 0.5f);
    float fx0 = floorf(px), fy0 = floorf(py);
    float fx = px - fx0, fy = py - fy0;
    unsigned ix = (unsigned)(int)fx0;
    unsigned iy = (unsigned)(int)fy0;
    unsigned hy0 = iy * PRIME;
    unsigned hy1 = hy0 + PRIME;                   // (iy+1)*PRIME mod 2^32
    unsigned h00 = (ix         ^ hy0) & (HSZ - 1);
    unsigned h01 = (ix         ^ hy1) & (HSZ - 1);
    unsigned h10 = ((ix + 1u)  ^ hy0) & (HSZ - 1);
    unsigned h11 = ((ix + 1u)  ^ hy1) & (HSZ - 1);
    uint2 v00 = tbl[h00];
    uint2 v01 = tbl[h01];
    uint2 v10 = tbl[h10];
    uint2 v11 = tbl[h11];
    float gx = 1.0f - fx, gy = 1.0f - fy;
    float w00 = gx * gy, w01 = gx * fy, w10 = fx * gy, w11 = fx * fy;
    float2 a00 = h2f(v00.x), b00 = h2f(v00.y);
    float2 a01 = h2f(v01.x), b01 = h2f(v01.y);
    float2 a10 = h2f(v10.x), b10 = h2f(v10.y);
    float2 a11 = h2f(v11.x), b11 = h2f(v11.y);
    float4 r;
    r.x = w00 * a00.x + w01 * a01.x + w10 * a10.x + w11 * a11.x;
    r.y = w00 * a00.y + w01 * a01.y + w10 * a10.y + w11 * a11.y;
    r.z = w00 * b00.x + w01 * b01.x + w10 * b10.x + w11 * b11.x;
    r.w = w00 * b00.y + w01 * b01.y + w10 * b10.y + w11 * b11.y;
    return r;
}

// Stage one level (64 KB) into LDS via direct global->LDS DMA, 4 x 16 B per
// thread. Dest is linear: per wave, base + lane*16 (the required pattern).
__device__ __forceinline__ void stage_dma(const float4* __restrict__ src,
                                          float4* dst, int tid)
{
    #pragma unroll
    for (int k = 0; k < 4; ++k) {
        __builtin_amdgcn_global_load_lds(
            (const __attribute__((address_space(1))) unsigned int*)(src + tid + k * 1024),
            (__attribute__((address_space(3))) unsigned int*)(dst + tid + k * 1024),
            16, 0, 0);
    }
}

// 2 points/thread (2048 pts/block, 977 blocks), double-buffered 128 KB LDS.
// NO second launch_bounds arg: (1024,4) in the previous round capped VGPRs at
// 64 and spilled the 64-reg accumulator to scratch (+430 MB HBM writes).
// Pipeline per phase: issue next level's DMA -> s_waitcnt vmcnt(4) (waits ONLY
// the previous level's loads; the new 4 fly under this phase's gathers) ->
// s_barrier -> gather -> s_barrier. Raw barriers avoid __syncthreads' full
// vmcnt(0) drain that serialized staging in round 0.
__global__ __launch_bounds__(1024) void encode_kernel(
    const float* __restrict__ x, const float4* __restrict__ bt,
    float* __restrict__ out, int npts, Scales sc)
{
    __shared__ float4 smem[2][4096];              // 2 x 64 KB double buffer
    int tid = threadIdx.x;
    int base = blockIdx.x * 2048 + tid;
    int n0 = base, n1 = base + 1024;
    int c0 = n0 < npts ? n0 : npts - 1;
    int c1 = n1 < npts ? n1 : npts - 1;
    float2 p0 = ((const float2*)x)[c0];
    float2 p1 = ((const float2*)x)[c1];

    float4 acc0[NLV], acc1[NLV];                  // 64 VGPRs of accumulator

    // prologue: DMA level 0 into buffer 0
    stage_dma(bt, smem[0], tid);

    #pragma unroll
    for (int l = 0; l < NLV; ++l) {
        // issue next level's DMA first: in flight during this phase's gathers
        if (l < NLV - 1)
            stage_dma(bt + (size_t)(l + 1) * 4096, smem[(l + 1) & 1], tid);

        // wait for the PREVIOUS level's 4 loads (this buffer); leave the 4
        // just-issued ones outstanding. Final phase has nothing new: drain.
        if (l < NLV - 1) asm volatile("s_waitcnt vmcnt(4)" ::: "memory");
        else             asm volatile("s_waitcnt vmcnt(0)" ::: "memory");
        __builtin_amdgcn_s_barrier();             // all waves' slices landed
        __builtin_amdgcn_sched_barrier(0);        // no ds_read hoists above

        const uint2* tbl = (const uint2*)smem[l & 1];
        float scale = sc.s[l];
        acc0[l] = gather_lvl(tbl, p0, scale);
        acc1[l] = gather_lvl(tbl, p1, scale);

        // all waves done reading this buffer before next phase's DMA
        // overwrites it
        if (l < NLV - 1) {
            __builtin_amdgcn_sched_barrier(0);
            __builtin_amdgcn_s_barrier();
        }
    }

    // full 128-B line per point, 8 contiguous float4 stores back-to-back
    // (round-0-proven: L2 merges these into full lines, WRITE = ideal)
    if (n0 < npts) {
        float4* o = (float4*)(out + (size_t)n0 * 32);
        #pragma unroll
        for (int l = 0; l < NLV; ++l) o[l] = acc0[l];
    }
    if (n1 < npts) {
        float4* o = (float4*)(out + (size_t)n1 * 32);
        #pragma unroll
        for (int l = 0; l < NLV; ++l) o[l] = acc1[l];
    }
}

extern "C" void kernel_launch(void* const* d_in, const int* in_sizes, int n_in,
                              void* d_out, int out_size, void* d_ws, size_t ws_size,
                              hipStream_t stream) {
    const float* x     = (const float*)d_in[0];
    const float* t     = (const float*)d_in[1];
    const float* table = (const float*)d_in[2];
    float* out = (float*)d_out;
    __half2* bt = (__half2*)d_ws;       // 512 KB blended fp16 table

    int npts = in_sizes[0] / 2;

    Scales sc;
    const double l2p = log2(32768.0 / 512.0) / 7.0;   // exactly as numpy
    for (int l = 0; l < NLV; ++l)
        sc.s[l] = (float)(exp2((double)l * l2p) * 512.0 - 1.0);

    blend_kernel<<<(NLV * HSZ) / 256, 256, 0, stream>>>(table, t, bt);

    int nblocks = (npts + 2047) / 2048;
    encode_kernel<<<nblocks, 1024, 0, stream>>>(
        x, (const float4*)bt, out, npts, sc);
}

// Round 4
// 369.782 us; speedup vs baseline: 1.2459x; 1.1309x over previous
//
#include <hip/hip_runtime.h>
#include <hip/hip_fp16.h>
#include <math.h>

#define NLV 8
#define NF 4
#define HSZ 8192
#define TRES 25
#define PRIME 2654435761u

struct Scales { float s[NLV]; };

// Blend two time slices into one fp16 table in workspace.
// Layout per level l: 8192 slots x 8 B, slot h = {half2(f0,f1), half2(f2,f3)}
// -> one ds_read_b64 per bilinear corner in the encode kernel.
__global__ __launch_bounds__(256) void blend_kernel(
    const float* __restrict__ table, const float* __restrict__ tptr,
    __half2* __restrict__ bt)
{
    int i = blockIdx.x * 256 + threadIdx.x;       // 0..65535 = l*8192 + h
    float t = *tptr;
    float idx = t * (float)(TRES - 1);            // fp32, matches ref
    float fi1 = floorf(idx);
    float fi2 = ceilf(idx);
    float w2 = idx - fi1;
    float w1 = 1.0f - w2;
    size_t off1 = (size_t)(int)fi1 * (size_t)(NLV * HSZ * NF);
    size_t off2 = (size_t)(int)fi2 * (size_t)(NLV * HSZ * NF);
    float4 a = ((const float4*)(table + off1))[i];
    float4 b = ((const float4*)(table + off2))[i];
    float4 r;
    r.x = w1 * a.x + w2 * b.x;
    r.y = w1 * a.y + w2 * b.y;
    r.z = w1 * a.z + w2 * b.z;
    r.w = w1 * a.w + w2 * b.w;
    bt[2 * (size_t)i]     = __floats2half2_rn(r.x, r.y);
    bt[2 * (size_t)i + 1] = __floats2half2_rn(r.z, r.w);
}

__device__ __forceinline__ float2 h2f(unsigned u) {
    return __half22float2(__builtin_bit_cast(__half2, u));
}

// One level, one point: 4 hashed corners, each an 8-B LDS read, bilinear blend.
__device__ __forceinline__ float4 gather_lvl(const uint2* tbl, float2 p, float scale)
{
    // separate mul+add rounding (no fma) to match numpy floor/frac exactly
    float px = __fadd_rn(__fmul_rn(p.x, scale), 0.5f);
    float py = __fadd_rn(__fmul_rn(p.y, scale), 0.5f);
    float fx0 = floorf(px), fy0 = floorf(py);
    float fx = px - fx0, fy = py - fy0;
    unsigned ix = (unsigned)(int)fx0;
    unsigned iy = (unsigned)(int)fy0;
    unsigned hy0 = iy * PRIME;
    unsigned hy1 = hy0 + PRIME;                   // (iy+1)*PRIME mod 2^32
    unsigned h00 = (ix         ^ hy0) & (HSZ - 1);
    unsigned h01 = (ix         ^ hy1) & (HSZ - 1);
    unsigned h10 = ((ix + 1u)  ^ hy0) & (HSZ - 1);
    unsigned h11 = ((ix + 1u)  ^ hy1) & (HSZ - 1);
    uint2 v00 = tbl[h00];
    uint2 v01 = tbl[h01];
    uint2 v10 = tbl[h10];
    uint2 v11 = tbl[h11];
    float gx = 1.0f - fx, gy = 1.0f - fy;
    float w00 = gx * gy, w01 = gx * fy, w10 = fx * gy, w11 = fx * fy;
    float2 a00 = h2f(v00.x), b00 = h2f(v00.y);
    float2 a01 = h2f(v01.x), b01 = h2f(v01.y);
    float2 a10 = h2f(v10.x), b10 = h2f(v10.y);
    float2 a11 = h2f(v11.x), b11 = h2f(v11.y);
    float4 r;
    r.x = w00 * a00.x + w01 * a01.x + w10 * a10.x + w11 * a11.x;
    r.y = w00 * a00.y + w01 * a01.y + w10 * a10.y + w11 * a11.y;
    r.z = w00 * b00.x + w01 * b01.x + w10 * b10.x + w11 * b11.x;
    r.w = w00 * b00.y + w01 * b01.y + w10 * b10.y + w11 * b11.y;
    return r;
}

// Stage one level (64 KB) into LDS via direct global->LDS DMA, 4 x 16 B per
// thread. Dest is linear: per wave, base + lane*16 (the required pattern).
__device__ __forceinline__ void stage_dma(const float4* __restrict__ src,
                                          float4* dst, int tid)
{
    #pragma unroll
    for (int k = 0; k < 4; ++k) {
        __builtin_amdgcn_global_load_lds(
            (const __attribute__((address_space(1))) unsigned int*)(src + tid + k * 1024),
            (__attribute__((address_space(3))) unsigned int*)(dst + tid + k * 1024),
            16, 0, 0);
    }
}

// 1 point/thread, double-buffered 128 KB LDS, DMA staging, counted vmcnt.
// KEY CHANGE vs rounds 1-3: NO local arrays. The accumulator is 8 named
// float4 scalars (macro-unrolled phases). Rounds 1-3 all had the acc array
// left in scratch (alloca never promoted with 1024-thread blocks) -> 256 B
// of scratch write+read per thread = the entire excess HBM traffic.
// 1 pt/thread keeps live state ~56 VGPRs (round-0-proven fit).
// amdgpu_waves_per_eu(4,4): occupancy is LDS-capped at 4 waves/EU anyway;
// tell the allocator its true budget (128 VGPRs), not a heuristic 64.
__global__ __launch_bounds__(1024)
__attribute__((amdgpu_waves_per_eu(4, 4)))
void encode_kernel(
    const float* __restrict__ x, const float4* __restrict__ bt,
    float* __restrict__ out, int npts, Scales sc)
{
    __shared__ float4 smem[2][4096];              // 2 x 64 KB double buffer
    int tid = threadIdx.x;
    int n0 = blockIdx.x * 1024 + tid;
    int c0 = n0 < npts ? n0 : npts - 1;           // clamp reads; store guarded
    float2 p = ((const float2*)x)[c0];

    // prologue: DMA level 0 into buffer 0
    stage_dma(bt, smem[0], tid);

    float4 a0, a1, a2, a3, a4, a5, a6, a7;

    // Per phase: issue next level's DMA -> s_waitcnt vmcnt(4) (waits ONLY the
    // previous level's 4 loads; the 4 just issued stay in flight under this
    // phase's gathers) -> s_barrier -> gather -> s_barrier (protect the buffer
    // the NEXT phase's DMA overwrites). Raw barriers avoid __syncthreads'
    // full vmcnt(0) drain.
#define PHASE(L, ACC)                                                        \
    {                                                                        \
        if ((L) < NLV - 1)                                                   \
            stage_dma(bt + (size_t)((L) + 1) * 4096, smem[((L) + 1) & 1], tid);\
        if ((L) < NLV - 1) asm volatile("s_waitcnt vmcnt(4)" ::: "memory");  \
        else               asm volatile("s_waitcnt vmcnt(0)" ::: "memory");  \
        __builtin_amdgcn_s_barrier();                                        \
        __builtin_amdgcn_sched_barrier(0);                                   \
        ACC = gather_lvl((const uint2*)smem[(L) & 1], p, sc.s[(L)]);         \
        if ((L) < NLV - 1) {                                                 \
            __builtin_amdgcn_sched_barrier(0);                               \
            __builtin_amdgcn_s_barrier();                                    \
        }                                                                    \
    }

    PHASE(0, a0)
    PHASE(1, a1)
    PHASE(2, a2)
    PHASE(3, a3)
    PHASE(4, a4)
    PHASE(5, a5)
    PHASE(6, a6)
    PHASE(7, a7)
#undef PHASE

    // full 128-B line per point, 8 contiguous float4 stores back-to-back
    if (n0 < npts) {
        float4* o = (float4*)(out + (size_t)n0 * 32);
        o[0] = a0; o[1] = a1; o[2] = a2; o[3] = a3;
        o[4] = a4; o[5] = a5; o[6] = a6; o[7] = a7;
    }
}

extern "C" void kernel_launch(void* const* d_in, const int* in_sizes, int n_in,
                              void* d_out, int out_size, void* d_ws, size_t ws_size,
                              hipStream_t stream) {
    const float* x     = (const float*)d_in[0];
    const float* t     = (const float*)d_in[1];
    const float* table = (const float*)d_in[2];
    float* out = (float*)d_out;
    __half2* bt = (__half2*)d_ws;       // 512 KB blended fp16 table

    int npts = in_sizes[0] / 2;

    Scales sc;
    const double l2p = log2(32768.0 / 512.0) / 7.0;   // exactly as numpy
    for (int l = 0; l < NLV; ++l)
        sc.s[l] = (float)(exp2((double)l * l2p) * 512.0 - 1.0);

    blend_kernel<<<(NLV * HSZ) / 256, 256, 0, stream>>>(table, t, bt);

    int nblocks = (npts + 1023) / 1024;
    encode_kernel<<<nblocks, 1024, 0, stream>>>(
        x, (const float4*)bt, out, npts, sc);
}